// Round 11
// baseline (194.250 us; speedup 1.0000x reference)
//
#include <hip/hip_runtime.h>
#include <hip/hip_bf16.h>
#include <stdint.h>

typedef __attribute__((ext_vector_type(8))) short bf16x8;   // 8 bf16 = 4 VGPRs
typedef __attribute__((ext_vector_type(4))) float f32x4;
typedef __attribute__((ext_vector_type(4))) unsigned u32x4;

#define MFMA16(A,B,C) __builtin_amdgcn_mfma_f32_16x16x32_bf16(A,B,C,0,0,0)

// Fragment layouts (verified m89/m91 ladder):
//  A-frag: lane l holds A[m=l&15][k=(l>>4)*8+j], j=0..7   (k-contiguous)
//  B-frag: lane l holds B^T[n=l&15][k=(l>>4)*8+j]         (k-contiguous)
//  C/D:    lane l reg r holds D[m=(l>>4)*4+r][n=l&15]

// async 16B global->LDS
__device__ inline void gld_lds16(const __hip_bfloat16* g, __hip_bfloat16* l) {
  __builtin_amdgcn_global_load_lds(
      (const __attribute__((address_space(1))) void*)g,
      (__attribute__((address_space(3))) void*)l, 16, 0, 0);
}

// pack two f32 -> one b32 holding (bf16(a) | bf16(b)<<16)
__device__ inline unsigned pkbf(float a, float b) {
  __hip_bfloat162 t = __float22bfloat162_rn(float2{a, b});
  return *(unsigned*)&t;
}

// Quad redistribution for the S^T->A-frag transform.
__device__ inline void quad_mix(unsigned &a, unsigned &b) {
#if __has_builtin(__builtin_amdgcn_permlane32_swap) && __has_builtin(__builtin_amdgcn_permlane16_swap)
  auto r1 = __builtin_amdgcn_permlane32_swap(a, b, false, false);
  auto r2 = __builtin_amdgcn_permlane16_swap(r1[0], r1[1], false, false);
  a = r2[0];
  b = r2[1];
#else
  int lane = (int)(threadIdx.x & 63);
  int g = lane >> 4;
  int lm = lane & 15;
  int slo = (((g << 1) & 3) << 4) | lm;
  int shi = ((((g << 1) | 1) & 3) << 4) | lm;
  unsigned t0 = (unsigned)__shfl((int)a, slo, 64);
  unsigned t1 = (unsigned)__shfl((int)b, slo, 64);
  unsigned t2 = (unsigned)__shfl((int)a, shi, 64);
  unsigned t3 = (unsigned)__shfl((int)b, shi, 64);
  bool hi = g >= 2;
  unsigned na = hi ? t1 : t0;
  unsigned nb = hi ? t3 : t2;
  a = na;
  b = nb;
#endif
}

// ---------------------------------------------------------------------------
// f32 -> bf16 bulk convert (one-time; x / W_attn / W_proj)
// ---------------------------------------------------------------------------
__global__ __launch_bounds__(256)
void cvt_bf16(const float* __restrict__ s0, __hip_bfloat16* __restrict__ d0, int n0,
              const float* __restrict__ s1, __hip_bfloat16* __restrict__ d1, int n1,
              const float* __restrict__ s2, __hip_bfloat16* __restrict__ d2, int n2)
{
  const float* s; __hip_bfloat16* d; int n;
  if      (blockIdx.y == 0) { s = s0; d = d0; n = n0; }
  else if (blockIdx.y == 1) { s = s1; d = d1; n = n1; }
  else                      { s = s2; d = d2; n = n2; }
  int idx = (blockIdx.x * 256 + threadIdx.x) * 8;
  if (idx >= n) return;
  float4 u0 = *(const float4*)(s + idx);
  float4 u1 = *(const float4*)(s + idx + 4);
  __hip_bfloat16 t[8];
  t[0] = __float2bfloat16(u0.x); t[1] = __float2bfloat16(u0.y);
  t[2] = __float2bfloat16(u0.z); t[3] = __float2bfloat16(u0.w);
  t[4] = __float2bfloat16(u1.x); t[5] = __float2bfloat16(u1.y);
  t[6] = __float2bfloat16(u1.z); t[7] = __float2bfloat16(u1.w);
  *(int4*)(d + idx) = *(const int4*)t;
}

// ---------------------------------------------------------------------------
// GEMM (bf16): C[m][n] = sum_k A[m*K+k]*B[n*K+k] (+bias[n])
// BMxBN tile, BK=64, XOR-8 swizzled LDS staging, XCD-aware block swizzle.
// EPILOGUE REPACK (r8, -13us): bf16 C rows and vtg transpose go through a
// two-pass per-wave LDS repack (32 rows x stride-72 scratch overlaid on
// As/Bs after a post-k-loop __syncthreads): scalar/int2 ds_writes ->
// lgkmcnt(0)+sched_barrier -> ds_read_b128 -> global dwordx4 = every HBM
// store is a 128B row segment. Bit-identical math.
// VT (gemm1/QKV): V third (bn>=2048) -> vtg (transposed) via repack;
//   Q third (bn<1024) pre-scaled by (1/8)*log2(e).
// FUSE (gemm2): A = (Opar0+Opar1)*(1/(l0+l1)) built in regs during staging.
// r9 lesson: 256^2-tile port = 192 blocks < 256 CUs -> 25% chip idle,
// regressed +6us. This 128^2/768-block geometry is the right one here.
// ---------------------------------------------------------------------------
template<int BM, int BN, typename TC, bool VT, bool FUSE>
__global__ __launch_bounds__(256)
void gemm_bt(const __hip_bfloat16* __restrict__ A,
             const __hip_bfloat16* __restrict__ B,
             TC* __restrict__ C,
             const float* __restrict__ bias,
             __hip_bfloat16* __restrict__ vtg,
             const float* __restrict__ pl,
             int M, int N, int K)
{
  constexpr int MI  = BM / 32;
  constexpr int NJ  = BN / 32;
  constexpr int ACH = BM * 8;                 // A chunks (8 x 16B per row)
  constexpr int NP  = (BM + BN) * 8 / 256;    // chunks per thread

  __shared__ __align__(16) __hip_bfloat16 smem[(BM + BN) * 64];
  __hip_bfloat16* As = smem;
  __hip_bfloat16* Bs = smem + BM * 64;

  const int tid  = threadIdx.x;
  const int lane = tid & 63;
  const int w    = tid >> 6;
  const int lm   = lane & 15;
  const int g    = lane >> 4;
  const int sx   = lm & 7;                    // LDS read swizzle

  // XCD-aware bijective block swizzle (requires nwg % 8 == 0)
  int bxs = blockIdx.x, bys = blockIdx.y;
  {
    const int nwg = gridDim.x * gridDim.y;
    if ((nwg & 7) == 0) {
      int lid = bys * gridDim.x + bxs;
      int nl = (lid & 7) * (nwg >> 3) + (lid >> 3);
      bxs = nl % gridDim.x;
      bys = nl / gridDim.x;
    }
  }
  const int bm = bys * BM;
  const int bn = bxs * BN;
  const int rm = (w >> 1) * (BM / 2);
  const int cn = (w & 1) * (BN / 2);

  const f32x4 fzero = {0.0f, 0.0f, 0.0f, 0.0f};
  f32x4 acc[MI][NJ];
  for (int i = 0; i < MI; i++)
    for (int j = 0; j < NJ; j++)
      acc[i][j] = fzero;

  for (int k0 = 0; k0 < K; k0 += 64) {
    __syncthreads();
#pragma unroll
    for (int p = 0; p < NP; p++) {
      int c = tid + p * 256;
      if (c < ACH) {
        int row = c >> 3, sl = c & 7, gc = sl ^ (row & 7);
        if constexpr (FUSE) {
          // A = (po0 + po1) * 1/(l0 + l1), built in regs -> LDS (swizzled slot)
          int grow = bm + row;
          int col  = k0 + gc * 8;
          int hh   = col >> 6;
          float li = pl[grow * 16 + hh] + pl[(size_t)M * 16 + grow * 16 + hh];
          float rinv = 1.0f / li;
          int4 ra = *(const int4*)&A[(size_t)grow * K + col];
          int4 rb = *(const int4*)&A[(size_t)M * K + (size_t)grow * K + col];
          const __hip_bfloat16* pa = (const __hip_bfloat16*)&ra;
          const __hip_bfloat16* pb = (const __hip_bfloat16*)&rb;
          __hip_bfloat16 tt[8];
#pragma unroll
          for (int jj = 0; jj < 8; jj++)
            tt[jj] = __float2bfloat16(
                (__bfloat162float(pa[jj]) + __bfloat162float(pb[jj])) * rinv);
          *(int4*)&As[c * 8] = *(const int4*)tt;
        } else {
          gld_lds16(&A[(size_t)(bm + row) * K + k0 + gc * 8], &As[c * 8]);
        }
      } else {
        int cb = c - ACH;
        int row = cb >> 3, sl = cb & 7, gc = sl ^ (row & 7);
        gld_lds16(&B[(size_t)(bn + row) * K + k0 + gc * 8], &Bs[cb * 8]);
      }
    }
    __syncthreads();

    // two K=32 sub-steps per staged tile (e = k-chunk half)
#pragma unroll
    for (int e = 0; e < 2; e++) {
      bf16x8 af[MI], bfr[NJ];
#pragma unroll
      for (int i = 0; i < MI; i++)
        af[i] = *(const bf16x8*)
            &As[(rm + 16 * i + lm) * 64 + ((4 * e + g) ^ sx) * 8];
#pragma unroll
      for (int j = 0; j < NJ; j++)
        bfr[j] = *(const bf16x8*)
            &Bs[(cn + 16 * j + lm) * 64 + ((4 * e + g) ^ sx) * 8];
#pragma unroll
      for (int i = 0; i < MI; i++)
#pragma unroll
        for (int j = 0; j < NJ; j++)
          acc[i][j] = MFMA16(af[i], bfr[j], acc[i][j]);
    }
  }

  // ---- epilogues ----
  if constexpr (VT) {
    if (vtg != nullptr && bn >= 2048) {
      // transposed output via per-wave two-pass LDS repack -> 128B row stores
      __syncthreads();                        // all waves done reading As/Bs
      __hip_bfloat16* scr = smem + w * (32 * 72);
      const int vh = (bn + cn - 2048) >> 6;   // wave-uniform head
      const int m0 = bm + rm;
      const int bb = m0 >> 11, t0 = m0 & 2047;
      const int cc = lane & 7, rl = lane >> 3;
#pragma unroll
      for (int p = 0; p < 2; p++) {
#pragma unroll
        for (int jj = 0; jj < 2; jj++) {
          int j = 2 * p + jj;                 // dd = 32p + 16jj + lm
#pragma unroll
          for (int i = 0; i < MI; i++) {
            __hip_bfloat16 t4[4];
#pragma unroll
            for (int r = 0; r < 4; r++) t4[r] = __float2bfloat16(acc[i][j][r]);
            *(int2*)&scr[(16 * jj + lm) * 72 + 16 * i + 4 * g] =
                *(const int2*)t4;
          }
        }
        asm volatile("s_waitcnt lgkmcnt(0)" ::: "memory");
        __builtin_amdgcn_sched_barrier(0);
#pragma unroll
        for (int it = 0; it < 4; it++) {
          int lr = it * 8 + rl;               // local dd row 0..31
          int dd = 32 * p + lr;
          int4 vrow = *(const int4*)&scr[lr * 72 + cc * 8];
          *(int4*)&vtg[((size_t)(bb * 16 + vh) * 64 + dd) * 2048 + t0 + cc * 8] =
              vrow;
        }
        asm volatile("s_waitcnt lgkmcnt(0)" ::: "memory");
        __builtin_amdgcn_sched_barrier(0);
      }
      return;
    }
  }

  // Q pre-scale: 1/sqrt(64) * log2(e)  (softmax becomes exp2)
  const float qs = (VT && vtg != nullptr && bn < 1024)
                       ? (0.125f * 1.4426950408889634f) : 1.0f;

  if constexpr (sizeof(TC) == 2 && MI == 4) {
    // bf16 C-write via per-wave two-pass LDS repack -> 128B row stores
    __syncthreads();                          // all waves done reading As/Bs
    __hip_bfloat16* scr = smem + w * (32 * 72);
    const int cc = lane & 7, rl = lane >> 3;
#pragma unroll
    for (int p = 0; p < 2; p++) {
#pragma unroll
      for (int ii = 0; ii < 2; ii++) {
        int i = 2 * p + ii;                   // rows 32p + 16ii + 4g + r
#pragma unroll
        for (int j = 0; j < NJ; j++) {
          float bv = bias ? bias[bn + cn + 16 * j + lm] : 0.0f;
#pragma unroll
          for (int r = 0; r < 4; r++) {
            float v = acc[i][j][r] * qs + bv;
            scr[(16 * ii + 4 * g + r) * 72 + 16 * j + lm] = __float2bfloat16(v);
          }
        }
      }
      asm volatile("s_waitcnt lgkmcnt(0)" ::: "memory");
      __builtin_amdgcn_sched_barrier(0);
#pragma unroll
      for (int it = 0; it < 4; it++) {
        int lr = it * 8 + rl;
        int rowm = bm + rm + 32 * p + lr;
        int4 vrow = *(const int4*)&scr[lr * 72 + cc * 8];
        *(int4*)&C[(size_t)rowm * N + bn + cn + cc * 8] = vrow;
      }
      asm volatile("s_waitcnt lgkmcnt(0)" ::: "memory");
      __builtin_amdgcn_sched_barrier(0);
    }
    return;
  }

  // f32 (or small-tile) path: direct stores
#pragma unroll
  for (int j = 0; j < NJ; j++) {
    int coln = bn + cn + 16 * j + lm;
    float bv = bias ? bias[coln] : 0.0f;
#pragma unroll
    for (int i = 0; i < MI; i++) {
#pragma unroll
      for (int r = 0; r < 4; r++) {
        int rowm = bm + rm + 16 * i + 4 * g + r;
        float v = acc[i][j][r] * qs + bv;
        if constexpr (sizeof(TC) == 2)
          C[(size_t)rowm * N + coln] = __float2bfloat16(v);
        else
          C[(size_t)rowm * N + coln] = v;
      }
    }
  }
}

// ---------------------------------------------------------------------------
// MHA, no-max softmax, S^T formulation.
//   S^T = K·Q^T ; p = exp2(s) ; P->A-frag via quad_mix ; O = P·V ; l = P·1.
// Block = (b,h) x 128 q; wave owns 32 q (2 mt tiles); kv-step 64.
// PLATEAU (9 nulls at ~56us) on scheduling/traffic levers. r11 lever is the
// RESIDENCY CAP: VGPR_Count excludes acc-side regs (r1 evidence: cap-64 pin
// reported VGPR=32, i.e. 32+32 combined); this kernel is ~72+64 = ~136
// combined -> only 3 waves/SIMD (512/136). __launch_bounds__(256,4) caps
// combined at 128 -- an ~8-reg trim (NOT r1's 64-cap collapse) -> 4 waves/
// SIMD (+33% TLP), 4 blocks/CU x 32KB LDS = 128KB <= 160 OK.
// Guard: FETCH ~12.5MB / WRITE ~20.5MB must not balloon (spill signature).
// ---------------------------------------------------------------------------
__global__ __launch_bounds__(256, 4)
void mha(const __hip_bfloat16* __restrict__ qkv,
         const __hip_bfloat16* __restrict__ vtg,
         __hip_bfloat16* __restrict__ yout,
         __hip_bfloat16* __restrict__ po,
         float* __restrict__ pl,
         int nsteps)
{
  const int T = 2048, F = 3072, Cc = 1024;
  const int bh = blockIdx.x;
  const int b  = bh >> 4, h = bh & 15;
  const int qb0 = blockIdx.y * 128;
  const int z   = blockIdx.z;
  const int kvb = z * 64 * nsteps;

  const int tid  = threadIdx.x;
  const int lane = tid & 63;
  const int w    = tid >> 6;
  const int lm   = lane & 15;
  const int g    = lane >> 4;

  __shared__ __align__(16) __hip_bfloat16 Ks[2][64 * 64];   // 16 KB
  __shared__ __align__(16) __hip_bfloat16 Vs[2][64 * 64];   // 16 KB

  const size_t rowbase = (size_t)b * T * F;
  const int hoff = h * 64;
  const __hip_bfloat16* Kbase = qkv + rowbase + 1024 + hoff;
  const __hip_bfloat16* Vtb   = vtg + (size_t)(b * 16 + h) * 64 * 2048;

  const int qw = qb0 + 32 * w;
  bf16x8 aq[2][2];
#pragma unroll
  for (int mt = 0; mt < 2; mt++)
#pragma unroll
    for (int e = 0; e < 2; e++)
      aq[mt][e] = *(const bf16x8*)
          &qkv[rowbase + (size_t)(qw + 16 * mt + lm) * F + hoff + 32 * e + 8 * g];

  const f32x4 fzero = {0.0f, 0.0f, 0.0f, 0.0f};
  const short one_bf = (short)0x3f80;
  const bf16x8 vone = {one_bf, one_bf, one_bf, one_bf,
                       one_bf, one_bf, one_bf, one_bf};
  f32x4 yacc[2][4];
  f32x4 yl[2];
#pragma unroll
  for (int mt = 0; mt < 2; mt++) {
    yl[mt] = fzero;
#pragma unroll
    for (int c = 0; c < 4; c++) yacc[mt][c] = fzero;
  }

  const int sx = lm & 7;

  auto stage = [&](int tt, int bb) {
    const int kvn = kvb + tt * 64;
#pragma unroll
    for (int p = 0; p < 2; p++) {
      int c = tid + p * 256;
      int row = c >> 3, sl = c & 7, gc = sl ^ (row & 7);
      gld_lds16(Kbase + (size_t)(kvn + row) * F + gc * 8, &Ks[bb][c * 8]);
    }
#pragma unroll
    for (int p = 0; p < 2; p++) {
      int c = tid + p * 256;
      int row = c >> 3, sl = c & 7, gc = sl ^ (row & 7);
      gld_lds16(Vtb + (size_t)row * 2048 + kvn + gc * 8, &Vs[bb][c * 8]);
    }
  };

  stage(0, 0);

  for (int t = 0; t < nsteps; t++) {
    const int buf = t & 1;
    __syncthreads();
    if (t + 1 < nsteps) stage(t + 1, buf ^ 1);

    const __hip_bfloat16* Kb = Ks[buf];
    const __hip_bfloat16* Vb = Vs[buf];

    f32x4 st[2][4];
    __builtin_amdgcn_s_setprio(1);
#pragma unroll
    for (int c2 = 0; c2 < 4; c2++) {
      bf16x8 k0 = *(const bf16x8*)&Kb[(16 * c2 + lm) * 64 + ((0 + g) ^ sx) * 8];
      bf16x8 k1 = *(const bf16x8*)&Kb[(16 * c2 + lm) * 64 + ((4 + g) ^ sx) * 8];
      st[0][c2] = MFMA16(k0, aq[0][0], fzero);
      st[0][c2] = MFMA16(k1, aq[0][1], st[0][c2]);
      st[1][c2] = MFMA16(k0, aq[1][0], fzero);
      st[1][c2] = MFMA16(k1, aq[1][1], st[1][c2]);
    }
    __builtin_amdgcn_s_setprio(0);

    bf16x8 ap[2][2];
#pragma unroll
    for (int mt = 0; mt < 2; mt++) {
#pragma unroll
      for (int hf = 0; hf < 2; hf++) {
        unsigned pkv[2][2];
#pragma unroll
        for (int cc = 0; cc < 2; cc++) {
          const f32x4 &s4 = st[mt][2 * hf + cc];
#pragma unroll
          for (int u = 0; u < 2; u++) {
            float p0 = __builtin_amdgcn_exp2f(s4[2 * u]);
            float p1 = __builtin_amdgcn_exp2f(s4[2 * u + 1]);
            pkv[cc][u] = pkbf(p0, p1);
          }
        }
        unsigned f0 = pkv[0][0], f2 = pkv[1][0];
        quad_mix(f0, f2);
        unsigned f1 = pkv[0][1], f3 = pkv[1][1];
        quad_mix(f1, f3);
        u32x4 fv = {f0, f1, f2, f3};
        ap[mt][hf] = __builtin_bit_cast(bf16x8, fv);
      }
    }

    __builtin_amdgcn_s_setprio(1);
#pragma unroll
    for (int c = 0; c < 4; c++) {
#pragma unroll
      for (int hf = 0; hf < 2; hf++) {
        bf16x8 bv = *(const bf16x8*)
            &Vb[(16 * c + lm) * 64 + (((hf << 2) | g) ^ sx) * 8];
        yacc[0][c] = MFMA16(ap[0][hf], bv, yacc[0][c]);
        yacc[1][c] = MFMA16(ap[1][hf], bv, yacc[1][c]);
      }
    }
#pragma unroll
    for (int mt = 0; mt < 2; mt++) {
      yl[mt] = MFMA16(ap[mt][0], vone, yl[mt]);
      yl[mt] = MFMA16(ap[mt][1], vone, yl[mt]);
    }
    __builtin_amdgcn_s_setprio(0);
  }

#pragma unroll
  for (int mt = 0; mt < 2; mt++) {
    if (yout != nullptr) {
      float rv[4];
#pragma unroll
      for (int r = 0; r < 4; r++)
        rv[r] = 1.0f / yl[mt][r];
#pragma unroll
      for (int c = 0; c < 4; c++)
#pragma unroll
        for (int r = 0; r < 4; r++) {
          int qrow = qw + 16 * mt + 4 * g + r;
          yout[(size_t)(b * T + qrow) * Cc + hoff + 16 * c + lm] =
              __float2bfloat16(yacc[mt][c][r] * rv[r]);
        }
    } else {
      __hip_bfloat16* pz = po + (size_t)z * 4096 * 1024;
      float* plz = pl + (size_t)z * 4096 * 16;
#pragma unroll
      for (int c = 0; c < 4; c++)
#pragma unroll
        for (int r = 0; r < 4; r++) {
          int qrow = qw + 16 * mt + 4 * g + r;
          pz[(size_t)(b * T + qrow) * Cc + hoff + 16 * c + lm] =
              __float2bfloat16(yacc[mt][c][r]);
        }
      if (lm == 0) {
#pragma unroll
        for (int r = 0; r < 4; r++)
          plz[(b * T + qw + 16 * mt + 4 * g + r) * 16 + h] = yl[mt][r];
      }
    }
  }
}

// ---------------------------------------------------------------------------
extern "C" void kernel_launch(void* const* d_in, const int* in_sizes, int n_in,
                              void* d_out, int out_size, void* d_ws, size_t ws_size,
                              hipStream_t stream)
{
  const float* x  = (const float*)d_in[0];   // [2,2048,1024]
  const float* Wa = (const float*)d_in[1];   // [3072,1024]
  const float* Wp = (const float*)d_in[2];   // [1024,1024]
  const float* bp = (const float*)d_in[3];   // [1024]
  float* out = (float*)d_out;                // [2,2048,1024] f32

  const int BT = 4096, C = 1024, F3 = 3072;
  char* ws = (char*)d_ws;
  __hip_bfloat16* qkv  = (__hip_bfloat16*)ws;                // 25.2 MB (V third unused)
  __hip_bfloat16* vtg  = (__hip_bfloat16*)(ws + 25165824);   // 8.4 MB V^T
  __hip_bfloat16* xbf  = (__hip_bfloat16*)(ws + 33554432);   // 8.4 MB
  __hip_bfloat16* yb   = xbf;  // z=1 fallback: mha writes y here
  __hip_bfloat16* Wabf = (__hip_bfloat16*)(ws + 41943040);   // 6.3 MB
  __hip_bfloat16* Wpbf = (__hip_bfloat16*)(ws + 48234496);   // 2.1 MB
  __hip_bfloat16* Opar = (__hip_bfloat16*)(ws + 50331648);   // 2 x 8.4 MB
  float*          lpar = (float*)(ws + 67108864);            // 2 x 256 KB
  const size_t need_split = 67633152;

  cvt_bf16<<<dim3(2048, 3), 256, 0, stream>>>(
      x, xbf, BT * C, Wa, Wabf, F3 * C, Wp, Wpbf, C * C);
  gemm_bt<128, 128, __hip_bfloat16, true, false>
      <<<dim3(F3 / 128, BT / 128), 256, 0, stream>>>(xbf, Wabf, qkv, nullptr, vtg,
                                                     nullptr, BT, F3, C);
  if (ws_size >= need_split) {
    // split-kv 2-way, kv-step 64 -> 16 steps/block; bh-fastest grid order.
    mha<<<dim3(32, 16, 2), 256, 0, stream>>>(qkv, vtg, nullptr, Opar, lpar, 16);
    // gemm2 with fused combine: A = (Opar0+Opar1)/(l0+l1) built during staging.
    gemm_bt<64, 128, float, false, true>
        <<<dim3(C / 128, BT / 64), 256, 0, stream>>>(Opar, Wpbf, out, bp,
                                                     nullptr, lpar, BT, C, C);
  } else {
    mha<<<dim3(32, 16, 1), 256, 0, stream>>>(qkv, vtg, yb, nullptr, nullptr, 32);
    gemm_bt<64, 128, float, false, false>
        <<<dim3(C / 128, BT / 64), 256, 0, stream>>>(yb, Wpbf, out, bp,
                                                     nullptr, nullptr, BT, C, C);
  }
}

// Round 12
// 186.099 us; speedup vs baseline: 1.0438x; 1.0438x over previous
//
#include <hip/hip_runtime.h>
#include <hip/hip_bf16.h>
#include <stdint.h>

typedef __attribute__((ext_vector_type(8))) short bf16x8;   // 8 bf16 = 4 VGPRs
typedef __attribute__((ext_vector_type(4))) float f32x4;
typedef __attribute__((ext_vector_type(4))) unsigned u32x4;

#define MFMA16(A,B,C) __builtin_amdgcn_mfma_f32_16x16x32_bf16(A,B,C,0,0,0)

// Fragment layouts (verified m89/m91 ladder):
//  A-frag: lane l holds A[m=l&15][k=(l>>4)*8+j], j=0..7   (k-contiguous)
//  B-frag: lane l holds B^T[n=l&15][k=(l>>4)*8+j]         (k-contiguous)
//  C/D:    lane l reg r holds D[m=(l>>4)*4+r][n=l&15]

// async 16B global->LDS
__device__ inline void gld_lds16(const __hip_bfloat16* g, __hip_bfloat16* l) {
  __builtin_amdgcn_global_load_lds(
      (const __attribute__((address_space(1))) void*)g,
      (__attribute__((address_space(3))) void*)l, 16, 0, 0);
}

// pack two f32 -> one b32 holding (bf16(a) | bf16(b)<<16)
__device__ inline unsigned pkbf(float a, float b) {
  __hip_bfloat162 t = __float22bfloat162_rn(float2{a, b});
  return *(unsigned*)&t;
}

// Quad redistribution for the S^T->A-frag transform.
__device__ inline void quad_mix(unsigned &a, unsigned &b) {
#if __has_builtin(__builtin_amdgcn_permlane32_swap) && __has_builtin(__builtin_amdgcn_permlane16_swap)
  auto r1 = __builtin_amdgcn_permlane32_swap(a, b, false, false);
  auto r2 = __builtin_amdgcn_permlane16_swap(r1[0], r1[1], false, false);
  a = r2[0];
  b = r2[1];
#else
  int lane = (int)(threadIdx.x & 63);
  int g = lane >> 4;
  int lm = lane & 15;
  int slo = (((g << 1) & 3) << 4) | lm;
  int shi = ((((g << 1) | 1) & 3) << 4) | lm;
  unsigned t0 = (unsigned)__shfl((int)a, slo, 64);
  unsigned t1 = (unsigned)__shfl((int)b, slo, 64);
  unsigned t2 = (unsigned)__shfl((int)a, shi, 64);
  unsigned t3 = (unsigned)__shfl((int)b, shi, 64);
  bool hi = g >= 2;
  unsigned na = hi ? t1 : t0;
  unsigned nb = hi ? t3 : t2;
  a = na;
  b = nb;
#endif
}

// ---------------------------------------------------------------------------
// f32 -> bf16 bulk convert (one-time; x / W_attn / W_proj)
// ---------------------------------------------------------------------------
__global__ __launch_bounds__(256)
void cvt_bf16(const float* __restrict__ s0, __hip_bfloat16* __restrict__ d0, int n0,
              const float* __restrict__ s1, __hip_bfloat16* __restrict__ d1, int n1,
              const float* __restrict__ s2, __hip_bfloat16* __restrict__ d2, int n2)
{
  const float* s; __hip_bfloat16* d; int n;
  if      (blockIdx.y == 0) { s = s0; d = d0; n = n0; }
  else if (blockIdx.y == 1) { s = s1; d = d1; n = n1; }
  else                      { s = s2; d = d2; n = n2; }
  int idx = (blockIdx.x * 256 + threadIdx.x) * 8;
  if (idx >= n) return;
  float4 u0 = *(const float4*)(s + idx);
  float4 u1 = *(const float4*)(s + idx + 4);
  __hip_bfloat16 t[8];
  t[0] = __float2bfloat16(u0.x); t[1] = __float2bfloat16(u0.y);
  t[2] = __float2bfloat16(u0.z); t[3] = __float2bfloat16(u0.w);
  t[4] = __float2bfloat16(u1.x); t[5] = __float2bfloat16(u1.y);
  t[6] = __float2bfloat16(u1.z); t[7] = __float2bfloat16(u1.w);
  *(int4*)(d + idx) = *(const int4*)t;
}

// ---------------------------------------------------------------------------
// GEMM (bf16): C[m][n] = sum_k A[m*K+k]*B[n*K+k] (+bias[n])
// BMxBN tile, BK=64, XOR-8 swizzled LDS staging, XCD-aware block swizzle.
// EPILOGUE REPACK (r8, -13us): bf16 C rows and vtg transpose go through a
// two-pass per-wave LDS repack (32 rows x stride-72 scratch overlaid on
// As/Bs after a post-k-loop __syncthreads): scalar/int2 ds_writes ->
// lgkmcnt(0)+sched_barrier -> ds_read_b128 -> global dwordx4 = every HBM
// store is a 128B row segment. Bit-identical math.
// VT (gemm1/QKV): V third (bn>=2048) -> vtg (transposed) via repack;
//   Q third (bn<1024) pre-scaled by (1/8)*log2(e).
// FUSE (gemm2): A = (Opar0+Opar1)*(1/(l0+l1)) built in regs during staging.
// r9 lesson: 256^2-tile port = 192 blocks < 256 CUs -> 25% chip idle.
// r12: __launch_bounds__(256,4) = combined-register cap 128 (VGPR+acc on the
// unified file). Combined live set ~124-134 straddles the 4-waves/SIMD
// boundary; the pin trims a few regs (r11: 8-reg trim was spill-free on mha,
// 58->50us) instead of silently dropping to 3 waves/SIMD. No-op if already
// under. Guard: gemm FETCH must not balloon (spill signature).
// ---------------------------------------------------------------------------
template<int BM, int BN, typename TC, bool VT, bool FUSE>
__global__ __launch_bounds__(256, 4)
void gemm_bt(const __hip_bfloat16* __restrict__ A,
             const __hip_bfloat16* __restrict__ B,
             TC* __restrict__ C,
             const float* __restrict__ bias,
             __hip_bfloat16* __restrict__ vtg,
             const float* __restrict__ pl,
             int M, int N, int K)
{
  constexpr int MI  = BM / 32;
  constexpr int NJ  = BN / 32;
  constexpr int ACH = BM * 8;                 // A chunks (8 x 16B per row)
  constexpr int NP  = (BM + BN) * 8 / 256;    // chunks per thread

  __shared__ __align__(16) __hip_bfloat16 smem[(BM + BN) * 64];
  __hip_bfloat16* As = smem;
  __hip_bfloat16* Bs = smem + BM * 64;

  const int tid  = threadIdx.x;
  const int lane = tid & 63;
  const int w    = tid >> 6;
  const int lm   = lane & 15;
  const int g    = lane >> 4;
  const int sx   = lm & 7;                    // LDS read swizzle

  // XCD-aware bijective block swizzle (requires nwg % 8 == 0)
  int bxs = blockIdx.x, bys = blockIdx.y;
  {
    const int nwg = gridDim.x * gridDim.y;
    if ((nwg & 7) == 0) {
      int lid = bys * gridDim.x + bxs;
      int nl = (lid & 7) * (nwg >> 3) + (lid >> 3);
      bxs = nl % gridDim.x;
      bys = nl / gridDim.x;
    }
  }
  const int bm = bys * BM;
  const int bn = bxs * BN;
  const int rm = (w >> 1) * (BM / 2);
  const int cn = (w & 1) * (BN / 2);

  const f32x4 fzero = {0.0f, 0.0f, 0.0f, 0.0f};
  f32x4 acc[MI][NJ];
  for (int i = 0; i < MI; i++)
    for (int j = 0; j < NJ; j++)
      acc[i][j] = fzero;

  for (int k0 = 0; k0 < K; k0 += 64) {
    __syncthreads();
#pragma unroll
    for (int p = 0; p < NP; p++) {
      int c = tid + p * 256;
      if (c < ACH) {
        int row = c >> 3, sl = c & 7, gc = sl ^ (row & 7);
        if constexpr (FUSE) {
          // A = (po0 + po1) * 1/(l0 + l1), built in regs -> LDS (swizzled slot)
          int grow = bm + row;
          int col  = k0 + gc * 8;
          int hh   = col >> 6;
          float li = pl[grow * 16 + hh] + pl[(size_t)M * 16 + grow * 16 + hh];
          float rinv = 1.0f / li;
          int4 ra = *(const int4*)&A[(size_t)grow * K + col];
          int4 rb = *(const int4*)&A[(size_t)M * K + (size_t)grow * K + col];
          const __hip_bfloat16* pa = (const __hip_bfloat16*)&ra;
          const __hip_bfloat16* pb = (const __hip_bfloat16*)&rb;
          __hip_bfloat16 tt[8];
#pragma unroll
          for (int jj = 0; jj < 8; jj++)
            tt[jj] = __float2bfloat16(
                (__bfloat162float(pa[jj]) + __bfloat162float(pb[jj])) * rinv);
          *(int4*)&As[c * 8] = *(const int4*)tt;
        } else {
          gld_lds16(&A[(size_t)(bm + row) * K + k0 + gc * 8], &As[c * 8]);
        }
      } else {
        int cb = c - ACH;
        int row = cb >> 3, sl = cb & 7, gc = sl ^ (row & 7);
        gld_lds16(&B[(size_t)(bn + row) * K + k0 + gc * 8], &Bs[cb * 8]);
      }
    }
    __syncthreads();

    // two K=32 sub-steps per staged tile (e = k-chunk half)
#pragma unroll
    for (int e = 0; e < 2; e++) {
      bf16x8 af[MI], bfr[NJ];
#pragma unroll
      for (int i = 0; i < MI; i++)
        af[i] = *(const bf16x8*)
            &As[(rm + 16 * i + lm) * 64 + ((4 * e + g) ^ sx) * 8];
#pragma unroll
      for (int j = 0; j < NJ; j++)
        bfr[j] = *(const bf16x8*)
            &Bs[(cn + 16 * j + lm) * 64 + ((4 * e + g) ^ sx) * 8];
#pragma unroll
      for (int i = 0; i < MI; i++)
#pragma unroll
        for (int j = 0; j < NJ; j++)
          acc[i][j] = MFMA16(af[i], bfr[j], acc[i][j]);
    }
  }

  // ---- epilogues ----
  if constexpr (VT) {
    if (vtg != nullptr && bn >= 2048) {
      // transposed output via per-wave two-pass LDS repack -> 128B row stores
      __syncthreads();                        // all waves done reading As/Bs
      __hip_bfloat16* scr = smem + w * (32 * 72);
      const int vh = (bn + cn - 2048) >> 6;   // wave-uniform head
      const int m0 = bm + rm;
      const int bb = m0 >> 11, t0 = m0 & 2047;
      const int cc = lane & 7, rl = lane >> 3;
#pragma unroll
      for (int p = 0; p < 2; p++) {
#pragma unroll
        for (int jj = 0; jj < 2; jj++) {
          int j = 2 * p + jj;                 // dd = 32p + 16jj + lm
#pragma unroll
          for (int i = 0; i < MI; i++) {
            __hip_bfloat16 t4[4];
#pragma unroll
            for (int r = 0; r < 4; r++) t4[r] = __float2bfloat16(acc[i][j][r]);
            *(int2*)&scr[(16 * jj + lm) * 72 + 16 * i + 4 * g] =
                *(const int2*)t4;
          }
        }
        asm volatile("s_waitcnt lgkmcnt(0)" ::: "memory");
        __builtin_amdgcn_sched_barrier(0);
#pragma unroll
        for (int it = 0; it < 4; it++) {
          int lr = it * 8 + rl;               // local dd row 0..31
          int dd = 32 * p + lr;
          int4 vrow = *(const int4*)&scr[lr * 72 + cc * 8];
          *(int4*)&vtg[((size_t)(bb * 16 + vh) * 64 + dd) * 2048 + t0 + cc * 8] =
              vrow;
        }
        asm volatile("s_waitcnt lgkmcnt(0)" ::: "memory");
        __builtin_amdgcn_sched_barrier(0);
      }
      return;
    }
  }

  // Q pre-scale: 1/sqrt(64) * log2(e)  (softmax becomes exp2)
  const float qs = (VT && vtg != nullptr && bn < 1024)
                       ? (0.125f * 1.4426950408889634f) : 1.0f;

  if constexpr (sizeof(TC) == 2 && MI == 4) {
    // bf16 C-write via per-wave two-pass LDS repack -> 128B row stores
    __syncthreads();                          // all waves done reading As/Bs
    __hip_bfloat16* scr = smem + w * (32 * 72);
    const int cc = lane & 7, rl = lane >> 3;
#pragma unroll
    for (int p = 0; p < 2; p++) {
#pragma unroll
      for (int ii = 0; ii < 2; ii++) {
        int i = 2 * p + ii;                   // rows 32p + 16ii + 4g + r
#pragma unroll
        for (int j = 0; j < NJ; j++) {
          float bv = bias ? bias[bn + cn + 16 * j + lm] : 0.0f;
#pragma unroll
          for (int r = 0; r < 4; r++) {
            float v = acc[i][j][r] * qs + bv;
            scr[(16 * ii + 4 * g + r) * 72 + 16 * j + lm] = __float2bfloat16(v);
          }
        }
      }
      asm volatile("s_waitcnt lgkmcnt(0)" ::: "memory");
      __builtin_amdgcn_sched_barrier(0);
#pragma unroll
      for (int it = 0; it < 4; it++) {
        int lr = it * 8 + rl;
        int rowm = bm + rm + 32 * p + lr;
        int4 vrow = *(const int4*)&scr[lr * 72 + cc * 8];
        *(int4*)&C[(size_t)rowm * N + bn + cn + cc * 8] = vrow;
      }
      asm volatile("s_waitcnt lgkmcnt(0)" ::: "memory");
      __builtin_amdgcn_sched_barrier(0);
    }
    return;
  }

  // f32 (or small-tile) path: direct stores
#pragma unroll
  for (int j = 0; j < NJ; j++) {
    int coln = bn + cn + 16 * j + lm;
    float bv = bias ? bias[coln] : 0.0f;
#pragma unroll
    for (int i = 0; i < MI; i++) {
#pragma unroll
      for (int r = 0; r < 4; r++) {
        int rowm = bm + rm + 16 * i + 4 * g + r;
        float v = acc[i][j][r] * qs + bv;
        if constexpr (sizeof(TC) == 2)
          C[(size_t)rowm * N + coln] = __float2bfloat16(v);
        else
          C[(size_t)rowm * N + coln] = v;
      }
    }
  }
}

// ---------------------------------------------------------------------------
// MHA, no-max softmax, S^T formulation.
//   S^T = K·Q^T ; p = exp2(s) ; P->A-frag via quad_mix ; O = P·V ; l = P·1.
// Block = (b,h) x 128 q; wave owns 32 q (2 mt tiles); kv-step 64.
// r11 WIN (58->50.4us): __launch_bounds__(256,4) = combined-register cap 128
// (VGPR_Count excludes acc-side on the unified file; was ~72+64=136 -> 3
// waves/SIMD). Pin trimmed arch 72->64, zero spill (FETCH/WRITE flat),
// occupancy 22->29.5% (=4/3x, the predicted 3->4 waves/SIMD step).
// Earlier plateau probes (9 nulls): DS diet, l-on-MFMA, z=4, counted vmcnt,
// setprio, kv-step 64, grid order -- all neutral; the register granule was
// the binding constraint. Do NOT pin tighter: r1's cap-64 = full spill.
// ---------------------------------------------------------------------------
__global__ __launch_bounds__(256, 4)
void mha(const __hip_bfloat16* __restrict__ qkv,
         const __hip_bfloat16* __restrict__ vtg,
         __hip_bfloat16* __restrict__ yout,
         __hip_bfloat16* __restrict__ po,
         float* __restrict__ pl,
         int nsteps)
{
  const int T = 2048, F = 3072, Cc = 1024;
  const int bh = blockIdx.x;
  const int b  = bh >> 4, h = bh & 15;
  const int qb0 = blockIdx.y * 128;
  const int z   = blockIdx.z;
  const int kvb = z * 64 * nsteps;

  const int tid  = threadIdx.x;
  const int lane = tid & 63;
  const int w    = tid >> 6;
  const int lm   = lane & 15;
  const int g    = lane >> 4;

  __shared__ __align__(16) __hip_bfloat16 Ks[2][64 * 64];   // 16 KB
  __shared__ __align__(16) __hip_bfloat16 Vs[2][64 * 64];   // 16 KB

  const size_t rowbase = (size_t)b * T * F;
  const int hoff = h * 64;
  const __hip_bfloat16* Kbase = qkv + rowbase + 1024 + hoff;
  const __hip_bfloat16* Vtb   = vtg + (size_t)(b * 16 + h) * 64 * 2048;

  const int qw = qb0 + 32 * w;
  bf16x8 aq[2][2];
#pragma unroll
  for (int mt = 0; mt < 2; mt++)
#pragma unroll
    for (int e = 0; e < 2; e++)
      aq[mt][e] = *(const bf16x8*)
          &qkv[rowbase + (size_t)(qw + 16 * mt + lm) * F + hoff + 32 * e + 8 * g];

  const f32x4 fzero = {0.0f, 0.0f, 0.0f, 0.0f};
  const short one_bf = (short)0x3f80;
  const bf16x8 vone = {one_bf, one_bf, one_bf, one_bf,
                       one_bf, one_bf, one_bf, one_bf};
  f32x4 yacc[2][4];
  f32x4 yl[2];
#pragma unroll
  for (int mt = 0; mt < 2; mt++) {
    yl[mt] = fzero;
#pragma unroll
    for (int c = 0; c < 4; c++) yacc[mt][c] = fzero;
  }

  const int sx = lm & 7;

  auto stage = [&](int tt, int bb) {
    const int kvn = kvb + tt * 64;
#pragma unroll
    for (int p = 0; p < 2; p++) {
      int c = tid + p * 256;
      int row = c >> 3, sl = c & 7, gc = sl ^ (row & 7);
      gld_lds16(Kbase + (size_t)(kvn + row) * F + gc * 8, &Ks[bb][c * 8]);
    }
#pragma unroll
    for (int p = 0; p < 2; p++) {
      int c = tid + p * 256;
      int row = c >> 3, sl = c & 7, gc = sl ^ (row & 7);
      gld_lds16(Vtb + (size_t)row * 2048 + kvn + gc * 8, &Vs[bb][c * 8]);
    }
  };

  stage(0, 0);

  for (int t = 0; t < nsteps; t++) {
    const int buf = t & 1;
    __syncthreads();
    if (t + 1 < nsteps) stage(t + 1, buf ^ 1);

    const __hip_bfloat16* Kb = Ks[buf];
    const __hip_bfloat16* Vb = Vs[buf];

    f32x4 st[2][4];
    __builtin_amdgcn_s_setprio(1);
#pragma unroll
    for (int c2 = 0; c2 < 4; c2++) {
      bf16x8 k0 = *(const bf16x8*)&Kb[(16 * c2 + lm) * 64 + ((0 + g) ^ sx) * 8];
      bf16x8 k1 = *(const bf16x8*)&Kb[(16 * c2 + lm) * 64 + ((4 + g) ^ sx) * 8];
      st[0][c2] = MFMA16(k0, aq[0][0], fzero);
      st[0][c2] = MFMA16(k1, aq[0][1], st[0][c2]);
      st[1][c2] = MFMA16(k0, aq[1][0], fzero);
      st[1][c2] = MFMA16(k1, aq[1][1], st[1][c2]);
    }
    __builtin_amdgcn_s_setprio(0);

    bf16x8 ap[2][2];
#pragma unroll
    for (int mt = 0; mt < 2; mt++) {
#pragma unroll
      for (int hf = 0; hf < 2; hf++) {
        unsigned pkv[2][2];
#pragma unroll
        for (int cc = 0; cc < 2; cc++) {
          const f32x4 &s4 = st[mt][2 * hf + cc];
#pragma unroll
          for (int u = 0; u < 2; u++) {
            float p0 = __builtin_amdgcn_exp2f(s4[2 * u]);
            float p1 = __builtin_amdgcn_exp2f(s4[2 * u + 1]);
            pkv[cc][u] = pkbf(p0, p1);
          }
        }
        unsigned f0 = pkv[0][0], f2 = pkv[1][0];
        quad_mix(f0, f2);
        unsigned f1 = pkv[0][1], f3 = pkv[1][1];
        quad_mix(f1, f3);
        u32x4 fv = {f0, f1, f2, f3};
        ap[mt][hf] = __builtin_bit_cast(bf16x8, fv);
      }
    }

    __builtin_amdgcn_s_setprio(1);
#pragma unroll
    for (int c = 0; c < 4; c++) {
#pragma unroll
      for (int hf = 0; hf < 2; hf++) {
        bf16x8 bv = *(const bf16x8*)
            &Vb[(16 * c + lm) * 64 + (((hf << 2) | g) ^ sx) * 8];
        yacc[0][c] = MFMA16(ap[0][hf], bv, yacc[0][c]);
        yacc[1][c] = MFMA16(ap[1][hf], bv, yacc[1][c]);
      }
    }
#pragma unroll
    for (int mt = 0; mt < 2; mt++) {
      yl[mt] = MFMA16(ap[mt][0], vone, yl[mt]);
      yl[mt] = MFMA16(ap[mt][1], vone, yl[mt]);
    }
    __builtin_amdgcn_s_setprio(0);
  }

#pragma unroll
  for (int mt = 0; mt < 2; mt++) {
    if (yout != nullptr) {
      float rv[4];
#pragma unroll
      for (int r = 0; r < 4; r++)
        rv[r] = 1.0f / yl[mt][r];
#pragma unroll
      for (int c = 0; c < 4; c++)
#pragma unroll
        for (int r = 0; r < 4; r++) {
          int qrow = qw + 16 * mt + 4 * g + r;
          yout[(size_t)(b * T + qrow) * Cc + hoff + 16 * c + lm] =
              __float2bfloat16(yacc[mt][c][r] * rv[r]);
        }
    } else {
      __hip_bfloat16* pz = po + (size_t)z * 4096 * 1024;
      float* plz = pl + (size_t)z * 4096 * 16;
#pragma unroll
      for (int c = 0; c < 4; c++)
#pragma unroll
        for (int r = 0; r < 4; r++) {
          int qrow = qw + 16 * mt + 4 * g + r;
          pz[(size_t)(b * T + qrow) * Cc + hoff + 16 * c + lm] =
              __float2bfloat16(yacc[mt][c][r]);
        }
      if (lm == 0) {
#pragma unroll
        for (int r = 0; r < 4; r++)
          plz[(b * T + qw + 16 * mt + 4 * g + r) * 16 + h] = yl[mt][r];
      }
    }
  }
}

// ---------------------------------------------------------------------------
extern "C" void kernel_launch(void* const* d_in, const int* in_sizes, int n_in,
                              void* d_out, int out_size, void* d_ws, size_t ws_size,
                              hipStream_t stream)
{
  const float* x  = (const float*)d_in[0];   // [2,2048,1024]
  const float* Wa = (const float*)d_in[1];   // [3072,1024]
  const float* Wp = (const float*)d_in[2];   // [1024,1024]
  const float* bp = (const float*)d_in[3];   // [1024]
  float* out = (float*)d_out;                // [2,2048,1024] f32

  const int BT = 4096, C = 1024, F3 = 3072;
  char* ws = (char*)d_ws;
  __hip_bfloat16* qkv  = (__hip_bfloat16*)ws;                // 25.2 MB (V third unused)
  __hip_bfloat16* vtg  = (__hip_bfloat16*)(ws + 25165824);   // 8.4 MB V^T
  __hip_bfloat16* xbf  = (__hip_bfloat16*)(ws + 33554432);   // 8.4 MB
  __hip_bfloat16* yb   = xbf;  // z=1 fallback: mha writes y here
  __hip_bfloat16* Wabf = (__hip_bfloat16*)(ws + 41943040);   // 6.3 MB
  __hip_bfloat16* Wpbf = (__hip_bfloat16*)(ws + 48234496);   // 2.1 MB
  __hip_bfloat16* Opar = (__hip_bfloat16*)(ws + 50331648);   // 2 x 8.4 MB
  float*          lpar = (float*)(ws + 67108864);            // 2 x 256 KB
  const size_t need_split = 67633152;

  cvt_bf16<<<dim3(2048, 3), 256, 0, stream>>>(
      x, xbf, BT * C, Wa, Wabf, F3 * C, Wp, Wpbf, C * C);
  gemm_bt<128, 128, __hip_bfloat16, true, false>
      <<<dim3(F3 / 128, BT / 128), 256, 0, stream>>>(xbf, Wabf, qkv, nullptr, vtg,
                                                     nullptr, BT, F3, C);
  if (ws_size >= need_split) {
    // split-kv 2-way, kv-step 64 -> 16 steps/block; bh-fastest grid order.
    mha<<<dim3(32, 16, 2), 256, 0, stream>>>(qkv, vtg, nullptr, Opar, lpar, 16);
    // gemm2 with fused combine: A = (Opar0+Opar1)/(l0+l1) built during staging.
    gemm_bt<64, 128, float, false, true>
        <<<dim3(C / 128, BT / 64), 256, 0, stream>>>(Opar, Wpbf, out, bp,
                                                     nullptr, lpar, BT, C, C);
  } else {
    mha<<<dim3(32, 16, 1), 256, 0, stream>>>(qkv, vtg, yb, nullptr, nullptr, 32);
    gemm_bt<64, 128, float, false, false>
        <<<dim3(C / 128, BT / 64), 256, 0, stream>>>(yb, Wpbf, out, bp,
                                                     nullptr, nullptr, BT, C, C);
  }
}